// Round 1
// baseline (357.372 us; speedup 1.0000x reference)
//
#include <hip/hip_runtime.h>

// CapsuleLayer dynamic routing, fully fused.
// x:  [B=256, N=1152, CIN=8]  fp32
// W:  [NCAPS=10, N=1152, CIN=8, COUT=16] fp32
// out:[NCAPS, B, 1, 1, COUT] fp32
//
// One block per (c,b). Each thread owns NPT=3 route nodes n, keeps
// priors p[n][16] in registers (48 VGPRs), and the 3 routing iterations
// are block reductions (wave shuffle + LDS cross-wave).

constexpr int NCAPS  = 10;
constexpr int BATCH  = 256;
constexpr int NROUTE = 1152;
constexpr int CIN    = 8;
constexpr int COUT   = 16;
constexpr int T      = 384;          // 6 waves
constexpr int NPT    = NROUTE / T;   // 3
constexpr int NWAVES = T / 64;       // 6

struct SMem {
    float red[NWAVES][COUT];
    float sred[NWAVES];
};

__device__ inline float wave_sum(float v) {
#pragma unroll
    for (int off = 32; off; off >>= 1) v += __shfl_xor(v, off, 64);
    return v;
}
__device__ inline float wave_max(float v) {
#pragma unroll
    for (int off = 32; off; off >>= 1) v = fmaxf(v, __shfl_xor(v, off, 64));
    return v;
}

// Block-reduce COUT partials; result broadcast to all threads in s[].
__device__ inline void block_sum16(SMem& sm, const float part[COUT], float s[COUT],
                                   int lane, int wid) {
    float tmp[COUT];
#pragma unroll
    for (int o = 0; o < COUT; ++o) tmp[o] = wave_sum(part[o]);
    __syncthreads();                       // protect red[] reuse
    if (lane == 0) {
#pragma unroll
        for (int o = 0; o < COUT; ++o) sm.red[wid][o] = tmp[o];
    }
    __syncthreads();
#pragma unroll
    for (int o = 0; o < COUT; ++o) {
        float acc = sm.red[0][o];
#pragma unroll
        for (int w = 1; w < NWAVES; ++w) acc += sm.red[w][o];
        s[o] = acc;                        // wave-uniform LDS reads: broadcast
    }
}

__device__ inline float block_sum1(SMem& sm, float v, int lane, int wid) {
    v = wave_sum(v);
    __syncthreads();
    if (lane == 0) sm.sred[wid] = v;
    __syncthreads();
    float acc = sm.sred[0];
#pragma unroll
    for (int w = 1; w < NWAVES; ++w) acc += sm.sred[w];
    return acc;
}

__device__ inline float block_max1(SMem& sm, float v, int lane, int wid) {
    v = wave_max(v);
    __syncthreads();
    if (lane == 0) sm.sred[wid] = v;
    __syncthreads();
    float acc = sm.sred[0];
#pragma unroll
    for (int w = 1; w < NWAVES; ++w) acc = fmaxf(acc, sm.sred[w]);
    return acc;
}

__device__ inline void squash16(const float s[COUT], float v[COUT]) {
    float sn = 0.f;
#pragma unroll
    for (int o = 0; o < COUT; ++o) sn += s[o] * s[o];
    // (sn/(1+sn)) * s / sqrt(sn)
    float scale = sn / ((1.f + sn) * sqrtf(sn));
#pragma unroll
    for (int o = 0; o < COUT; ++o) v[o] = s[o] * scale;
}

__global__ __launch_bounds__(T)
void capsule_routing_kernel(const float* __restrict__ x,
                            const float* __restrict__ Wt,
                            float* __restrict__ out) {
    __shared__ SMem sm;
    const int blk  = blockIdx.x;       // c*256 + b  (b fastest -> W[c] L2-hot)
    const int c    = blk >> 8;
    const int b    = blk & 255;
    const int tid  = threadIdx.x;
    const int lane = tid & 63;
    const int wid  = tid >> 6;

    // ---- priors: p[k][o] for n = tid + k*T -------------------------------
    float p[NPT][COUT];
    const float* xb = x  + (size_t)b * NROUTE * CIN;
    const float* Wc = Wt + (size_t)c * NROUTE * CIN * COUT;

#pragma unroll
    for (int k = 0; k < NPT; ++k) {
        const int n = tid + k * T;
        const float4* xp = reinterpret_cast<const float4*>(xb + (size_t)n * CIN);
        float4 x0 = xp[0], x1 = xp[1];
        float xi[CIN] = {x0.x, x0.y, x0.z, x0.w, x1.x, x1.y, x1.z, x1.w};
        const float4* wp =
            reinterpret_cast<const float4*>(Wc + (size_t)n * CIN * COUT);
#pragma unroll
        for (int o = 0; o < COUT; ++o) p[k][o] = 0.f;
#pragma unroll
        for (int i = 0; i < CIN; ++i) {
#pragma unroll
            for (int oq = 0; oq < COUT / 4; ++oq) {
                float4 w4 = wp[i * (COUT / 4) + oq];
                p[k][oq * 4 + 0] += xi[i] * w4.x;
                p[k][oq * 4 + 1] += xi[i] * w4.y;
                p[k][oq * 4 + 2] += xi[i] * w4.z;
                p[k][oq * 4 + 3] += xi[i] * w4.w;
            }
        }
    }

    float part[COUT], s[COUT], v[COUT], bl[NPT];

    // ---- iteration 0: probs uniform = 1/N --------------------------------
#pragma unroll
    for (int o = 0; o < COUT; ++o) {
        float a = p[0][o];
#pragma unroll
        for (int k = 1; k < NPT; ++k) a += p[k][o];
        part[o] = a;
    }
    block_sum16(sm, part, s, lane, wid);
#pragma unroll
    for (int o = 0; o < COUT; ++o) s[o] *= (1.0f / NROUTE);
    squash16(s, v);
#pragma unroll
    for (int k = 0; k < NPT; ++k) {
        float d = 0.f;
#pragma unroll
        for (int o = 0; o < COUT; ++o) d += p[k][o] * v[o];
        bl[k] = d;                       // logits after iter 0
    }

    // ---- iterations 1,2 ---------------------------------------------------
#pragma unroll
    for (int it = 1; it < 3; ++it) {
        float m = bl[0];
#pragma unroll
        for (int k = 1; k < NPT; ++k) m = fmaxf(m, bl[k]);
        m = block_max1(sm, m, lane, wid);

        float e[NPT], es = 0.f;
#pragma unroll
        for (int k = 0; k < NPT; ++k) { e[k] = expf(bl[k] - m); es += e[k]; }
        float Z = block_sum1(sm, es, lane, wid);
        float invZ = 1.0f / Z;

#pragma unroll
        for (int o = 0; o < COUT; ++o) {
            float a = e[0] * p[0][o];
#pragma unroll
            for (int k = 1; k < NPT; ++k) a += e[k] * p[k][o];
            part[o] = a;
        }
        block_sum16(sm, part, s, lane, wid);
#pragma unroll
        for (int o = 0; o < COUT; ++o) s[o] *= invZ;
        squash16(s, v);

        if (it < 2) {
#pragma unroll
            for (int k = 0; k < NPT; ++k) {
                float d = 0.f;
#pragma unroll
                for (int o = 0; o < COUT; ++o) d += p[k][o] * v[o];
                bl[k] += d;
            }
        }
    }

    // ---- write out[c, b, 0, 0, :] ----------------------------------------
    if (tid < COUT) out[(size_t)blk * COUT + tid] = v[tid];
}

extern "C" void kernel_launch(void* const* d_in, const int* in_sizes, int n_in,
                              void* d_out, int out_size, void* d_ws, size_t ws_size,
                              hipStream_t stream) {
    const float* x  = (const float*)d_in[0];
    const float* Wt = (const float*)d_in[1];
    float* out = (float*)d_out;
    capsule_routing_kernel<<<dim3(NCAPS * BATCH), dim3(T), 0, stream>>>(x, Wt, out);
}

// Round 2
// 146.242 us; speedup vs baseline: 2.4437x; 2.4437x over previous
//
#include <hip/hip_runtime.h>

// CapsuleLayer dynamic routing, fused, coalesced-lane layout.
// x:  [B=256, N=1152, CIN=8]  fp32
// W:  [NCAPS=10, N=1152, CIN=8, COUT=16] fp32
// out:[NCAPS, B, 1, 1, COUT] fp32
//
// Block = (c, pair of b). 512 threads = 8 waves.
// Lane mapping: nn = lane>>2 (16 route-nodes per wave), oq = lane&3
// (4 output-channel quads). Per step, the 8 waves cover 128 n; 9 steps
// cover N=1152. Each thread holds p[b][k][4] (72 VGPRs) — priors for
// its (n,oq) slice, 2 batches.
//
// W access: lane reads float4 at Wc + n*128 + i*16 + oq*4 -> each quad
// reads 64B contiguous; 16 quads at 512B stride = fully-utilized lines.
// x access: quad-uniform address -> hardware broadcast (no extra traffic).

constexpr int NCAPS  = 10;
constexpr int BATCH  = 256;
constexpr int NROUTE = 1152;
constexpr int CIN    = 8;
constexpr int COUT   = 16;
constexpr int T      = 512;             // 8 waves
constexpr int NWAVES = T / 64;
constexpr int BT     = 2;               // batches per block
constexpr int NSTEP  = NROUTE / (NWAVES * 16);   // 9 n's per thread
constexpr int BG     = BATCH / BT;      // 128 b-groups

struct SMem {
    float red16[NWAVES][BT][COUT];
    float redS[NWAVES][BT];
};

// Sum over the 16 nn-lane-groups within a wave (preserves oq), then
// across waves via LDS. part/sout indexed [b][j], j = lane's 4 o's.
__device__ inline void blk_red16(SMem& sm, float part[BT][4], float sout[BT][4],
                                 int lane, int wid, int oq) {
#pragma unroll
    for (int b = 0; b < BT; ++b)
#pragma unroll
        for (int j = 0; j < 4; ++j) {
            float t = part[b][j];
#pragma unroll
            for (int off = 4; off < 64; off <<= 1) t += __shfl_xor(t, off, 64);
            part[b][j] = t;
        }
    __syncthreads();                     // protect red16 reuse
    if (lane < 4) {                      // nn==0 lanes, lane == oq
#pragma unroll
        for (int b = 0; b < BT; ++b)
#pragma unroll
            for (int j = 0; j < 4; ++j) sm.red16[wid][b][lane * 4 + j] = part[b][j];
    }
    __syncthreads();
#pragma unroll
    for (int b = 0; b < BT; ++b)
#pragma unroll
        for (int j = 0; j < 4; ++j) {
            float acc = sm.red16[0][b][oq * 4 + j];
#pragma unroll
            for (int w = 1; w < NWAVES; ++w) acc += sm.red16[w][b][oq * 4 + j];
            sout[b][j] = acc;
        }
}

__device__ inline void squash2(const float s[BT][4], float v[BT][4]) {
#pragma unroll
    for (int b = 0; b < BT; ++b) {
        float sn = 0.f;
#pragma unroll
        for (int j = 0; j < 4; ++j) sn += s[b][j] * s[b][j];
        sn += __shfl_xor(sn, 1, 64);     // quad-reduce over oq -> full 16-sum
        sn += __shfl_xor(sn, 2, 64);
        float scale = sn / ((1.f + sn) * sqrtf(sn));
#pragma unroll
        for (int j = 0; j < 4; ++j) v[b][j] = s[b][j] * scale;
    }
}

__global__ __launch_bounds__(T, 2)
void capsule_routing_kernel(const float* __restrict__ x,
                            const float* __restrict__ Wt,
                            float* __restrict__ out) {
    __shared__ SMem sm;
    const int blk  = blockIdx.x;
    const int c    = blk / BG;
    const int bg   = blk % BG;
    const int b0   = bg * BT;
    const int tid  = threadIdx.x;
    const int lane = tid & 63;
    const int wid  = tid >> 6;
    const int nn   = lane >> 2;
    const int oq   = lane & 3;
    const int nbase = wid * 16 + nn;

    const float* Wc  = Wt + (size_t)c * NROUTE * CIN * COUT;
    const float* xb0 = x + (size_t)b0 * NROUTE * CIN;
    const float* xb1 = xb0 + NROUTE * CIN;

    // ---- priors ----------------------------------------------------------
    float p[BT][NSTEP][4];
#pragma unroll
    for (int k = 0; k < NSTEP; ++k) {
        const int n = k * 128 + nbase;
        const float4* wp = reinterpret_cast<const float4*>(Wc + (size_t)n * (CIN * COUT)) + oq;
        // x: quad-uniform addresses -> broadcast
        const float4* xp0 = reinterpret_cast<const float4*>(xb0 + (size_t)n * CIN);
        const float4* xp1 = reinterpret_cast<const float4*>(xb1 + (size_t)n * CIN);
        float4 xa = xp0[0], xbv = xp0[1];
        float4 xc = xp1[0], xdv = xp1[1];
        float xs0[CIN] = {xa.x, xa.y, xa.z, xa.w, xbv.x, xbv.y, xbv.z, xbv.w};
        float xs1[CIN] = {xc.x, xc.y, xc.z, xc.w, xdv.x, xdv.y, xdv.z, xdv.w};
#pragma unroll
        for (int j = 0; j < 4; ++j) { p[0][k][j] = 0.f; p[1][k][j] = 0.f; }
#pragma unroll
        for (int i = 0; i < CIN; ++i) {
            float4 w4 = wp[i * 4];       // i*16 floats = i*4 float4
            p[0][k][0] = fmaf(xs0[i], w4.x, p[0][k][0]);
            p[0][k][1] = fmaf(xs0[i], w4.y, p[0][k][1]);
            p[0][k][2] = fmaf(xs0[i], w4.z, p[0][k][2]);
            p[0][k][3] = fmaf(xs0[i], w4.w, p[0][k][3]);
            p[1][k][0] = fmaf(xs1[i], w4.x, p[1][k][0]);
            p[1][k][1] = fmaf(xs1[i], w4.y, p[1][k][1]);
            p[1][k][2] = fmaf(xs1[i], w4.z, p[1][k][2]);
            p[1][k][3] = fmaf(xs1[i], w4.w, p[1][k][3]);
        }
    }

    float part[BT][4], s[BT][4], v[BT][4], bl[BT][NSTEP], e[BT][NSTEP];

    // ---- iteration 0: probs uniform 1/N ---------------------------------
#pragma unroll
    for (int b = 0; b < BT; ++b)
#pragma unroll
        for (int j = 0; j < 4; ++j) {
            float a = 0.f;
#pragma unroll
            for (int k = 0; k < NSTEP; ++k) a += p[b][k][j];
            part[b][j] = a;
        }
    blk_red16(sm, part, s, lane, wid, oq);
#pragma unroll
    for (int b = 0; b < BT; ++b)
#pragma unroll
        for (int j = 0; j < 4; ++j) s[b][j] *= (1.0f / NROUTE);
    squash2(s, v);
#pragma unroll
    for (int b = 0; b < BT; ++b)
#pragma unroll
        for (int k = 0; k < NSTEP; ++k) {
            float d = 0.f;
#pragma unroll
            for (int j = 0; j < 4; ++j) d = fmaf(p[b][k][j], v[b][j], d);
            d += __shfl_xor(d, 1, 64);   // quad-sum over oq -> full 16-dot
            d += __shfl_xor(d, 2, 64);
            bl[b][k] = d;
        }

    // ---- iterations 1, 2 -------------------------------------------------
#pragma unroll
    for (int it = 1; it < 3; ++it) {
        // softmax max over n (duplicates across oq are harmless)
        float m[BT];
#pragma unroll
        for (int b = 0; b < BT; ++b) {
            float mm = bl[b][0];
#pragma unroll
            for (int k = 1; k < NSTEP; ++k) mm = fmaxf(mm, bl[b][k]);
#pragma unroll
            for (int off = 1; off < 64; off <<= 1) mm = fmaxf(mm, __shfl_xor(mm, off, 64));
            m[b] = mm;
        }
        __syncthreads();
        if (lane == 0) { sm.redS[wid][0] = m[0]; sm.redS[wid][1] = m[1]; }
        __syncthreads();
#pragma unroll
        for (int b = 0; b < BT; ++b) {
            float mm = sm.redS[0][b];
#pragma unroll
            for (int w = 1; w < NWAVES; ++w) mm = fmaxf(mm, sm.redS[w][b]);
            m[b] = mm;
        }

        // exp + Z (each n counted 4x across the quad -> invZ = 4/Z)
        float es[BT];
#pragma unroll
        for (int b = 0; b < BT; ++b) {
            float a = 0.f;
#pragma unroll
            for (int k = 0; k < NSTEP; ++k) { e[b][k] = __expf(bl[b][k] - m[b]); a += e[b][k]; }
#pragma unroll
            for (int off = 1; off < 64; off <<= 1) a += __shfl_xor(a, off, 64);
            es[b] = a;
        }
        __syncthreads();
        if (lane == 0) { sm.redS[wid][0] = es[0]; sm.redS[wid][1] = es[1]; }
        __syncthreads();
        float invZ[BT];
#pragma unroll
        for (int b = 0; b < BT; ++b) {
            float a = sm.redS[0][b];
#pragma unroll
            for (int w = 1; w < NWAVES; ++w) a += sm.redS[w][b];
            invZ[b] = 4.0f / a;
        }

        // s[o] = sum_n e*p / Z
#pragma unroll
        for (int b = 0; b < BT; ++b)
#pragma unroll
            for (int j = 0; j < 4; ++j) {
                float a = 0.f;
#pragma unroll
                for (int k = 0; k < NSTEP; ++k) a = fmaf(e[b][k], p[b][k][j], a);
                part[b][j] = a;
            }
        blk_red16(sm, part, s, lane, wid, oq);
#pragma unroll
        for (int b = 0; b < BT; ++b)
#pragma unroll
            for (int j = 0; j < 4; ++j) s[b][j] *= invZ[b];
        squash2(s, v);

        if (it < 2) {
#pragma unroll
            for (int b = 0; b < BT; ++b)
#pragma unroll
                for (int k = 0; k < NSTEP; ++k) {
                    float d = 0.f;
#pragma unroll
                    for (int j = 0; j < 4; ++j) d = fmaf(p[b][k][j], v[b][j], d);
                    d += __shfl_xor(d, 1, 64);
                    d += __shfl_xor(d, 2, 64);
                    bl[b][k] += d;
                }
        }
    }

    // ---- write out[c, b0..b0+1, 0, 0, :] ---------------------------------
    if (tid < 4) {                       // lane==oq==tid, nn=0, wave 0
        float4 o0 = make_float4(v[0][0], v[0][1], v[0][2], v[0][3]);
        float4 o1 = make_float4(v[1][0], v[1][1], v[1][2], v[1][3]);
        *reinterpret_cast<float4*>(out + ((size_t)(c * BATCH + b0) * COUT) + tid * 4) = o0;
        *reinterpret_cast<float4*>(out + ((size_t)(c * BATCH + b0 + 1) * COUT) + tid * 4) = o1;
    }
}

extern "C" void kernel_launch(void* const* d_in, const int* in_sizes, int n_in,
                              void* d_out, int out_size, void* d_ws, size_t ws_size,
                              hipStream_t stream) {
    const float* x  = (const float*)d_in[0];
    const float* Wt = (const float*)d_in[1];
    float* out = (float*)d_out;
    capsule_routing_kernel<<<dim3(NCAPS * BG), dim3(T), 0, stream>>>(x, Wt, out);
}